// Round 2
// baseline (468.053 us; speedup 1.0000x reference)
//
#include <hip/hip_runtime.h>

// SEST fused, v2: wave-synchronous persistent design.
// B=16384 F=39 E=64 R=13. Traffic: 164 MB read + 327 MB write -> ~78us @6.3TB/s.
// 1024 blocks x 256 thr = 4096 waves, all co-resident (4 blocks/CU).
// Each WAVE owns batch rows (4 per wave) with wave-private LDS scratch:
// no __syncthreads in the steady state (only one after weight staging).

#define B_TOT 16384
#define Fdim  39
#define Edim  64
#define Rdim  13
#define FR    (Fdim * Rdim)        // 507
#define NBLK  1024
#define WPB   4                    // waves per block
#define NWAVE (NBLK * WPB)         // 4096
#define BPW   (B_TOT / NWAVE)      // 4 rows per wave

typedef float f32x4 __attribute__((ext_vector_type(4)));

__global__ __launch_bounds__(256) void sest_kernel(
    const float* __restrict__ x,
    const float* __restrict__ W1,
    const float* __restrict__ W2,
    const float* __restrict__ W3,
    const float* __restrict__ W4,
    float* __restrict__ out)
{
    const int tid  = threadIdx.x;
    const int wid  = tid >> 6;
    const int lane = tid & 63;

    // weights staged once per block (read-only afterwards)
    __shared__ float Ws[4 * FR];                 // W1 | W2 | W3 | W4
    // wave-private scratch (no cross-wave sharing -> no barriers needed)
    __shared__ float ZmS[WPB][Fdim + 1];
    __shared__ float AmS[WPB][Fdim + 1];
    __shared__ float H1S[WPB][Rdim + 3];
    __shared__ float H2S[WPB][Rdim + 3];
    __shared__ float A2S[WPB][Fdim + 1];
    __shared__ float ThS[WPB][Fdim + 1];

    for (int i = tid; i < FR; i += 256) {
        Ws[i]          = W1[i];
        Ws[FR + i]     = W2[i];
        Ws[2 * FR + i] = W3[i];
        Ws[3 * FR + i] = W4[i];
    }
    __syncthreads();   // the only block-wide barrier

    float* Zm = ZmS[wid];
    float* Am = AmS[wid];
    float* H1 = H1S[wid];
    float* H2 = H2S[wid];
    float* A2 = A2S[wid];
    float* Th = ThS[wid];

    const int wave = blockIdx.x * WPB + wid;

    for (int bi = 0; bi < BPW; ++bi) {
        const int b = wave + bi * NWAVE;
        const f32x4* in4 = (const f32x4*)x + (size_t)b * (Fdim * Edim / 4);

        // ---- phase 1: load x into regs, per-row sum & abs-sum ----
        // 39 rows x 16 float4-slots = 624 work items over 10 wave-iterations
        f32x4 xr[10];
        #pragma unroll
        for (int it = 0; it < 10; ++it) {
            const int j = it * 64 + lane;
            const int f = j >> 4, s = j & 15;
            float px = 0.f, pa = 0.f;
            if (j < Fdim * 16) {
                f32x4 v = in4[f * 16 + s];
                xr[it] = v;
                px = v.x + v.y + v.z + v.w;
                pa = fabsf(v.x) + fabsf(v.y) + fabsf(v.z) + fabsf(v.w);
            }
            #pragma unroll
            for (int m = 1; m < 16; m <<= 1) {   // 16-lane group reduce
                px += __shfl_xor(px, m);
                pa += __shfl_xor(pa, m);
            }
            if (j < Fdim * 16 && s == 0) {
                Zm[f] = px * (1.0f / 64.0f);
                Am[f] = pa * (1.0f / 64.0f);
            }
        }
        __threadfence_block();   // order LDS write->read within the wave

        // ---- phase 2a: hidden layers (lanes 0-12: gate, 32-44: thres) ----
        if (lane < Rdim) {
            float acc = 0.f;
            #pragma unroll
            for (int f = 0; f < Fdim; ++f) acc += Zm[f] * Ws[f * Rdim + lane];
            H1[lane] = fmaxf(acc, 0.f);
        } else if (lane >= 32 && lane < 32 + Rdim) {
            const int r = lane - 32;
            float acc = 0.f;
            #pragma unroll
            for (int f = 0; f < Fdim; ++f) acc += Am[f] * Ws[2 * FR + f * Rdim + r];
            H2[r] = fmaxf(acc, 0.f);
        }
        __threadfence_block();

        // ---- phase 2b: output layers (lanes 0-38 do both dots) ----
        if (lane < Fdim) {
            float a = 0.f, t = 0.f;
            #pragma unroll
            for (int r = 0; r < Rdim; ++r) {
                a += H1[r] * Ws[FR + r * Fdim + lane];
                t += H2[r] * Ws[3 * FR + r * Fdim + lane];
            }
            A2[lane] = fmaxf(a, 0.f);
            Th[lane] = Am[lane] * fmaxf(t, 0.f);
        }
        __threadfence_block();

        // ---- phase 3: V = x*gate ; R = sign(x)*max(|x|-th,0) ----
        f32x4* o4 = (f32x4*)out + (size_t)b * (Fdim * 2 * Edim / 4);
        #pragma unroll
        for (int it = 0; it < 10; ++it) {
            const int j = it * 64 + lane;
            if (j < Fdim * 16) {
                const int f = j >> 4, s = j & 15;
                const float a2 = A2[f];
                const float th = Th[f];
                const f32x4 v = xr[it];
                f32x4 V, Rv;
                V.x = v.x * a2; V.y = v.y * a2; V.z = v.z * a2; V.w = v.w * a2;
                Rv.x = copysignf(fmaxf(fabsf(v.x) - th, 0.f), v.x);
                Rv.y = copysignf(fmaxf(fabsf(v.y) - th, 0.f), v.y);
                Rv.z = copysignf(fmaxf(fabsf(v.z) - th, 0.f), v.z);
                Rv.w = copysignf(fmaxf(fabsf(v.w) - th, 0.f), v.w);
                o4[f * 32 + s]      = V;   // V half of row f
                o4[f * 32 + 16 + s] = Rv;  // R half of row f
            }
        }
    }
}

extern "C" void kernel_launch(void* const* d_in, const int* in_sizes, int n_in,
                              void* d_out, int out_size, void* d_ws, size_t ws_size,
                              hipStream_t stream) {
    const float* x  = (const float*)d_in[0];
    const float* W1 = (const float*)d_in[1];
    const float* W2 = (const float*)d_in[2];
    const float* W3 = (const float*)d_in[3];
    const float* W4 = (const float*)d_in[4];
    float* out = (float*)d_out;

    sest_kernel<<<NBLK, 256, 0, stream>>>(x, W1, W2, W3, W4, out);
}